// Round 3
// baseline (839.485 us; speedup 1.0000x reference)
//
#include <hip/hip_runtime.h>

#define N_NODES 100000
#define D 64
#define N_EDGES 1000000

// One wave (64 lanes) per edge: lane l handles feature l.
// Gather feat[src] row (coalesced 256B) and atomic-add into agg[dst] row.
// unsafeAtomicAdd -> hardware global_atomic_add_f32 (never a CAS loop).
// 2-way manual unroll: two independent gather/atomic streams in flight.
template <bool COUNT>
__global__ __launch_bounds__(256) void scatter_kernel(
    const float* __restrict__ feat,
    const int* __restrict__ src,
    const int* __restrict__ dst,
    float* __restrict__ agg,
    int* __restrict__ cnt) {
    int wave = (blockIdx.x * blockDim.x + threadIdx.x) >> 6;
    int lane = threadIdx.x & 63;
    int nwaves = (gridDim.x * blockDim.x) >> 6;

    int e = wave;
    for (; e + nwaves < N_EDGES; e += 2 * nwaves) {
        int s0 = src[e];
        int d0 = dst[e];
        int s1 = src[e + nwaves];
        int d1 = dst[e + nwaves];
        float v0 = feat[(size_t)s0 * D + lane];
        float v1 = feat[(size_t)s1 * D + lane];
        unsafeAtomicAdd(&agg[(size_t)d0 * D + lane], v0);
        unsafeAtomicAdd(&agg[(size_t)d1 * D + lane], v1);
        if (COUNT && lane == 0) {
            atomicAdd(&cnt[d0], 1);
            atomicAdd(&cnt[d1], 1);
        }
    }
    if (e < N_EDGES) {
        int s = src[e];
        int d = dst[e];
        float v = feat[(size_t)s * D + lane];
        unsafeAtomicAdd(&agg[(size_t)d * D + lane], v);
        if (COUNT && lane == 0) atomicAdd(&cnt[d], 1);
    }
}

// One wave per node; lane j computes output feature j.
// W_l / W_r columns live in registers (128 VGPRs, statically indexed via
// full unroll); input row values broadcast across lanes with __shfl.
// out[n][j] = relu( sum_k mean[k]*Wl[k][j] + sum_k xin[k]*Wr[k][j] + b[j] )
// If FUSE_OUT: additionally out[n] = sum_j h[j]*Wc[j] + bc (wave reduction).
template <bool FUSE_OUT>
__global__ __launch_bounds__(256) void transform_kernel(
    const float* __restrict__ agg,
    const int* __restrict__ cnt,
    const float* __restrict__ xin,
    const float* __restrict__ Wl,
    const float* __restrict__ Wr,
    const float* __restrict__ b,
    const float* __restrict__ Wc,
    const float* __restrict__ bc,
    float* __restrict__ out) {
    int lane = threadIdx.x & 63;

    float wl[64], wr[64];
#pragma unroll
    for (int k = 0; k < 64; ++k) {
        wl[k] = Wl[k * 64 + lane];
        wr[k] = Wr[k * 64 + lane];
    }
    float bj = b[lane];
    float wcj = 0.0f, bcv = 0.0f;
    if (FUSE_OUT) {
        wcj = Wc[lane];  // Wc is [64,1]
        bcv = bc[0];
    }

    int wave = (blockIdx.x * blockDim.x + threadIdx.x) >> 6;
    int nwaves = (gridDim.x * blockDim.x) >> 6;
    for (int n = wave; n < N_NODES; n += nwaves) {
        float inv = 1.0f / fmaxf((float)cnt[n], 1.0f);
        float m = agg[(size_t)n * D + lane] * inv;
        float xv = xin[(size_t)n * D + lane];
        // two accumulators: halve the serial FMA dependency chain
        float accA = bj, accB = 0.0f;
#pragma unroll
        for (int k = 0; k < 64; ++k) {
            float a = __shfl(m, k);
            float x2 = __shfl(xv, k);
            accA = fmaf(a, wl[k], accA);
            accB = fmaf(x2, wr[k], accB);
        }
        float acc = fmaxf(accA + accB, 0.0f);  // relu
        if (FUSE_OUT) {
            float v = acc * wcj;
#pragma unroll
            for (int off = 32; off; off >>= 1) v += __shfl_xor(v, off);
            if (lane == 0) out[n] = v + bcv;
        } else {
            out[(size_t)n * D + lane] = acc;
        }
    }
}

extern "C" void kernel_launch(void* const* d_in, const int* in_sizes, int n_in,
                              void* d_out, int out_size, void* d_ws, size_t ws_size,
                              hipStream_t stream) {
    const float* x   = (const float*)d_in[0];
    const int* ei    = (const int*)d_in[1];  // [2, N_EDGES]; JAX x64-off -> int32
    const float* W1l = (const float*)d_in[2];
    const float* W1r = (const float*)d_in[3];
    const float* b1  = (const float*)d_in[4];
    const float* W2l = (const float*)d_in[5];
    const float* W2r = (const float*)d_in[6];
    const float* b2  = (const float*)d_in[7];
    const float* Wc  = (const float*)d_in[8];
    const float* bc  = (const float*)d_in[9];
    float* out = (float*)d_out;

    const int* src = ei;
    const int* dst = ei + N_EDGES;

    // Workspace layout: agg f32[N*64] | cnt i32[N] | h1 f32[N*64]  => ~51.6 MB
    float* agg = (float*)d_ws;
    int*   cnt = (int*)(agg + (size_t)N_NODES * D);
    float* h1  = (float*)(cnt + N_NODES);

    // 2048 blocks = 8192 waves = exactly the 256CU x 32waves/CU capacity.
    const int SCATTER_BLOCKS = 2048;
    const int TRANSFORM_BLOCKS = 1024;  // VGPR-limited occupancy anyway

    // ---- Layer 1 ----
    // zero agg + cnt (adjacent) in one memset
    hipMemsetAsync(agg, 0, (size_t)N_NODES * D * sizeof(float) + N_NODES * sizeof(int),
                   stream);
    scatter_kernel<true><<<SCATTER_BLOCKS, 256, 0, stream>>>(x, src, dst, agg, cnt);
    transform_kernel<false><<<TRANSFORM_BLOCKS, 256, 0, stream>>>(
        agg, cnt, x, W1l, W1r, b1, nullptr, nullptr, h1);

    // ---- Layer 2 (+ fused classifier) ----  (cnt survives; only agg re-zeroed)
    hipMemsetAsync(agg, 0, (size_t)N_NODES * D * sizeof(float), stream);
    scatter_kernel<false><<<SCATTER_BLOCKS, 256, 0, stream>>>(h1, src, dst, agg, cnt);
    transform_kernel<true><<<TRANSFORM_BLOCKS, 256, 0, stream>>>(
        agg, cnt, h1, W2l, W2r, b2, Wc, bc, out);
}